// Round 7
// baseline (572.371 us; speedup 1.0000x reference)
//
#include <hip/hip_runtime.h>

typedef unsigned short u16;
typedef short v8s __attribute__((ext_vector_type(8)));
typedef float v4f __attribute__((ext_vector_type(4)));

constexpr int Tn = 8192;   // tokens = B*S
constexpr int Dd = 1024;   // model dim
constexpr int Hh = 2048;   // hidden dim
constexpr int Ee = 8;      // experts
constexpr int NB = 32;     // histogram/scatter blocks
constexpr int MAXP = 17;   // ceil(max 128-row panels / 8); panels <= 128+8=136

// round-to-nearest-even f32 -> bf16 (inputs finite)
static __device__ __forceinline__ u16 f2bf(float v) {
  unsigned u = __float_as_uint(v);
  unsigned r = (u + 0x7fffu + ((u >> 16) & 1u)) >> 16;
  return (u16)r;
}

static __device__ __forceinline__ float bf2f(u16 v) {
  return __uint_as_float(((unsigned)v) << 16);
}

// async global -> LDS, 16B per lane; LDS dest = wave-uniform base + lane*16
static __device__ __forceinline__ void gload_lds16(const u16* g, u16* l) {
  __builtin_amdgcn_global_load_lds(
      (const __attribute__((address_space(1))) unsigned int*)g,
      (__attribute__((address_space(3))) unsigned int*)l, 16, 0, 0);
}

// in: fp32 [E][R][C]  ->  out: bf16 [E][C][R], 64x64 tiles
__global__ __launch_bounds__(512) void transpose_cvt_kernel(
    const float* __restrict__ in, u16* __restrict__ out, int R, int C) {
  __shared__ float tile[64][65];
  int e = blockIdx.z;
  const float* ip = in + (size_t)e * R * C;
  u16* op = out + (size_t)e * R * C;
  int c0 = blockIdx.x * 64, r0 = blockIdx.y * 64;
  int tx = threadIdx.x, ty = threadIdx.y;  // block (64,8)
  for (int i = ty; i < 64; i += 8)
    tile[i][tx] = ip[(size_t)(r0 + i) * C + c0 + tx];
  __syncthreads();
  for (int i = ty; i < 64; i += 8)
    op[(size_t)(c0 + i) * R + r0 + tx] = f2bf(tile[tx][i]);
}

// one wave per token; fused x->bf16 conversion; no global atomics
__global__ __launch_bounds__(256) void gating_kernel(
    const float* __restrict__ x, const float* __restrict__ Wg, const float* __restrict__ bg,
    int* __restrict__ topki, float* __restrict__ topkw, u16* __restrict__ xb) {
  int lane = threadIdx.x & 63;
  int t = blockIdx.x * 4 + (threadIdx.x >> 6);
  const float4* xr = reinterpret_cast<const float4*>(x + (size_t)t * Dd);
  float acc[8] = {0.f, 0.f, 0.f, 0.f, 0.f, 0.f, 0.f, 0.f};
#pragma unroll
  for (int it = 0; it < 4; ++it) {
    float4 xv = xr[it * 64 + lane];
    int r = it * 256 + lane * 4;
    ushort4 o;
    o.x = f2bf(xv.x); o.y = f2bf(xv.y); o.z = f2bf(xv.z); o.w = f2bf(xv.w);
    *reinterpret_cast<ushort4*>(xb + (size_t)t * Dd + r) = o;
    const float4* wr = reinterpret_cast<const float4*>(Wg + (size_t)r * 8);
    float xs[4] = {xv.x, xv.y, xv.z, xv.w};
#pragma unroll
    for (int q = 0; q < 4; ++q) {
      float4 a = wr[q * 2], b = wr[q * 2 + 1];
      acc[0] += xs[q] * a.x; acc[1] += xs[q] * a.y; acc[2] += xs[q] * a.z; acc[3] += xs[q] * a.w;
      acc[4] += xs[q] * b.x; acc[5] += xs[q] * b.y; acc[6] += xs[q] * b.z; acc[7] += xs[q] * b.w;
    }
  }
#pragma unroll
  for (int e = 0; e < 8; ++e) {
#pragma unroll
    for (int off = 32; off > 0; off >>= 1) acc[e] += __shfl_xor(acc[e], off, 64);
  }
  if (lane == 0) {
    float l[8];
    float mx = -1e30f;
#pragma unroll
    for (int e = 0; e < 8; ++e) { l[e] = acc[e] + bg[e]; mx = fmaxf(mx, l[e]); }
    int i0 = 0;
#pragma unroll
    for (int e = 1; e < 8; ++e) if (l[e] > l[i0]) i0 = e;
    int i1 = (i0 == 0) ? 1 : 0;
#pragma unroll
    for (int e = 0; e < 8; ++e) if (e != i0 && l[e] > l[i1]) i1 = e;
    float e0 = __expf(l[i0] - mx), e1 = __expf(l[i1] - mx);
    float inv = 1.0f / (e0 + e1);
    topki[2 * t] = i0; topki[2 * t + 1] = i1;
    topkw[2 * t] = e0 * inv; topkw[2 * t + 1] = e1 * inv;
  }
}

// per-block expert histogram via LDS atomics; 8 global stores per block
__global__ __launch_bounds__(256) void hist_kernel(const int* __restrict__ topki,
                                                   int* __restrict__ blockcnt) {
  __shared__ int bins[8];
  int tid = threadIdx.x, b = blockIdx.x;
  if (tid < 8) bins[tid] = 0;
  __syncthreads();
  atomicAdd(&bins[topki[b * 512 + tid]], 1);
  atomicAdd(&bins[topki[b * 512 + 256 + tid]], 1);
  __syncthreads();
  if (tid < 8) blockcnt[b * 8 + tid] = bins[tid];
}

// prefix sums + XCD-pinned 128-row panel work-list
__global__ void prefix_kernel(const int* __restrict__ blockcnt, int* __restrict__ offs,
                              int* __restrict__ blockstart,
                              int* __restrict__ panelE, int* __restrict__ panelB,
                              int* __restrict__ nPanels) {
  __shared__ int tmp[8][NB];
  __shared__ int tot[8];
  int tid = threadIdx.x;
  if (tid < 8) {
    int s = 0;
    for (int b = 0; b < NB; ++b) { tmp[tid][b] = s; s += blockcnt[b * 8 + tid]; }
    tot[tid] = s;
  }
  __syncthreads();
  if (tid == 0) {
    int o = 0;
    for (int e = 0; e < 8; ++e) { offs[e] = o; o += tot[e]; }
    offs[8] = o;
    int np = 0;
    for (int e = 0; e < 8; ++e) {
      for (int m0 = 0; m0 < tot[e]; m0 += 128) {
        panelE[np] = e;
        panelB[np] = offs[e] + m0;
        ++np;
      }
    }
    *nPanels = np;
  }
  __syncthreads();
  if (tid < 8)
    for (int b = 0; b < NB; ++b) blockstart[b * 8 + tid] = offs[tid] + tmp[tid][b];
}

// slot assignment with LDS-local ranks; zero global atomics
__global__ __launch_bounds__(256) void scatter_kernel(
    const int* __restrict__ topki, const int* __restrict__ blockstart,
    int* __restrict__ rows, int* __restrict__ slotmap) {
  __shared__ int lbins[8];
  int tid = threadIdx.x, b = blockIdx.x;
  if (tid < 8) lbins[tid] = blockstart[b * 8 + tid];
  __syncthreads();
#pragma unroll
  for (int j = 0; j < 2; ++j) {
    int idx = b * 512 + j * 256 + tid;
    int e = topki[idx];
    int slot = atomicAdd(&lbins[e], 1);
    rows[slot] = idx >> 1;
    slotmap[idx] = slot;
  }
}

// ---- GEMM cores: 128x128 tile, BK=64, XOR-swizzled LDS, 4 blocks/CU target ----

// GEMM1: h[slot][n] = gelu( x[rows[slot]] @ W1[e] + b1[e] )
__global__ __launch_bounds__(256, 4) void gemm1_kernel(
    const u16* __restrict__ xb, const u16* __restrict__ w1t, const float* __restrict__ b1,
    const int* __restrict__ offs, const int* __restrict__ rows,
    const int* __restrict__ panelE, const int* __restrict__ panelB,
    const int* __restrict__ nPanels, u16* __restrict__ hbuf) {
  const int bid = blockIdx.x;
  const int xcd = bid & 7;
  const int q = bid >> 3;
  const int n = q & 15;               // Hh/128 = 16 n-blocks
  const int pi = (q >> 4) * 8 + xcd;
  if (pi >= *nPanels) return;
  const int e = panelE[pi];
  const int sbase = panelB[pi];
  const int lim = offs[e + 1];
  const int n0 = n * 128;

  __shared__ u16 As[128 * 64];        // 16 KB
  __shared__ u16 Bs[128 * 64];        // 16 KB

  const int tid = threadIdx.x;
  const int lane = tid & 63;
  const int wid = tid >> 6;
  const int wm = (wid >> 1) * 64;
  const int wn = (wid & 1) * 64;
  const int l16 = lane & 15;
  const int quad = lane >> 4;
  const int swz8 = (l16 & 7) * 8;     // read-side XOR mask (elems)

  const u16* aga[4];
  const u16* bga[4];
  u16* alds[4];
  u16* blds[4];
  const int lr = lane >> 3;                 // row within 8-row chunk
  const int g = (lane & 7) ^ (lr & 7);      // staged global k-chunk (XOR swizzle)
  const int kcol = g * 8;
#pragma unroll
  for (int j = 0; j < 4; ++j) {
    int chunk = wid * 4 + j;                // 0..15 covers rows [chunk*8, chunk*8+8)
    int rowl = chunk * 8 + lr;
    int slot = sbase + rowl;
    if (slot >= lim) slot = sbase;
    aga[j] = xb + (size_t)rows[slot] * Dd + kcol;
    bga[j] = w1t + ((size_t)e * Hh + n0 + rowl) * Dd + kcol;
    alds[j] = As + chunk * 512;             // 1 KB per wave-instruction
    blds[j] = Bs + chunk * 512;
  }

  v4f acc[4][4];
#pragma unroll
  for (int i = 0; i < 4; ++i)
#pragma unroll
    for (int j = 0; j < 4; ++j) acc[i][j] = {0.f, 0.f, 0.f, 0.f};

  int rowAoff[4], rowBoff[4];
#pragma unroll
  for (int t_ = 0; t_ < 4; ++t_) {
    rowAoff[t_] = (wm + t_ * 16 + l16) * 64;
    rowBoff[t_] = (wn + t_ * 16 + l16) * 64;
  }

  for (int k0 = 0; k0 < Dd; k0 += 64) {
    __syncthreads();
#pragma unroll
    for (int j = 0; j < 4; ++j) gload_lds16(aga[j] + k0, alds[j]);
#pragma unroll
    for (int j = 0; j < 4; ++j) gload_lds16(bga[j] + k0, blds[j]);
    __syncthreads();

#pragma unroll
    for (int s = 0; s < 2; ++s) {
      int coff = ((s * 4 + quad) * 8) ^ swz8;
      v8s a[4], b[4];
#pragma unroll
      for (int mt = 0; mt < 4; ++mt)
        a[mt] = *reinterpret_cast<const v8s*>(&As[rowAoff[mt] + coff]);
#pragma unroll
      for (int nt = 0; nt < 4; ++nt)
        b[nt] = *reinterpret_cast<const v8s*>(&Bs[rowBoff[nt] + coff]);
#pragma unroll
      for (int mt = 0; mt < 4; ++mt)
#pragma unroll
        for (int nt = 0; nt < 4; ++nt)
          acc[mt][nt] = __builtin_amdgcn_mfma_f32_16x16x32_bf16(a[mt], b[nt], acc[mt][nt], 0, 0, 0);
    }
  }

  float b1v[4];
  int ng[4];
#pragma unroll
  for (int nt = 0; nt < 4; ++nt) {
    ng[nt] = n0 + wn + nt * 16 + l16;
    b1v[nt] = b1[(size_t)e * Hh + ng[nt]];
  }
#pragma unroll
  for (int mt = 0; mt < 4; ++mt) {
#pragma unroll
    for (int i = 0; i < 4; ++i) {
      int m = wm + mt * 16 + quad * 4 + i;
      if (sbase + m < lim) {
        size_t rowbase = (size_t)(sbase + m) * Hh;
#pragma unroll
        for (int nt = 0; nt < 4; ++nt) {
          float v = acc[mt][nt][i] + b1v[nt];
          float s = 1.0f / (1.0f + __expf(-1.5957691216057308f * (v + 0.044715f * v * v * v)));
          hbuf[rowbase + ng[nt]] = f2bf(v * s);
        }
      }
    }
  }
}

// GEMM2: ybuf[slot][n] = h[slot] @ W2[e] + b2[e]
__global__ __launch_bounds__(256, 4) void gemm2_kernel(
    const u16* __restrict__ hbuf, const u16* __restrict__ w2t, const float* __restrict__ b2,
    const int* __restrict__ offs,
    const int* __restrict__ panelE, const int* __restrict__ panelB,
    const int* __restrict__ nPanels, u16* __restrict__ ybuf) {
  const int bid = blockIdx.x;
  const int xcd = bid & 7;
  const int q = bid >> 3;
  const int n = q & 7;                // Dd/128 = 8 n-blocks
  const int pi = (q >> 3) * 8 + xcd;
  if (pi >= *nPanels) return;
  const int e = panelE[pi];
  const int sbase = panelB[pi];
  const int lim = offs[e + 1];
  const int n0 = n * 128;

  __shared__ u16 As[128 * 64];
  __shared__ u16 Bs[128 * 64];

  const int tid = threadIdx.x;
  const int lane = tid & 63;
  const int wid = tid >> 6;
  const int wm = (wid >> 1) * 64;
  const int wn = (wid & 1) * 64;
  const int l16 = lane & 15;
  const int quad = lane >> 4;
  const int swz8 = (l16 & 7) * 8;

  const u16* aga[4];
  const u16* bga[4];
  u16* alds[4];
  u16* blds[4];
  const int lr = lane >> 3;
  const int g = (lane & 7) ^ (lr & 7);
  const int kcol = g * 8;
#pragma unroll
  for (int j = 0; j < 4; ++j) {
    int chunk = wid * 4 + j;
    int rowl = chunk * 8 + lr;
    int slot = sbase + rowl;
    if (slot >= lim) slot = sbase;
    aga[j] = hbuf + (size_t)slot * Hh + kcol;
    bga[j] = w2t + ((size_t)e * Dd + n0 + rowl) * Hh + kcol;
    alds[j] = As + chunk * 512;
    blds[j] = Bs + chunk * 512;
  }

  v4f acc[4][4];
#pragma unroll
  for (int i = 0; i < 4; ++i)
#pragma unroll
    for (int j = 0; j < 4; ++j) acc[i][j] = {0.f, 0.f, 0.f, 0.f};

  int rowAoff[4], rowBoff[4];
#pragma unroll
  for (int t_ = 0; t_ < 4; ++t_) {
    rowAoff[t_] = (wm + t_ * 16 + l16) * 64;
    rowBoff[t_] = (wn + t_ * 16 + l16) * 64;
  }

  for (int k0 = 0; k0 < Hh; k0 += 64) {
    __syncthreads();
#pragma unroll
    for (int j = 0; j < 4; ++j) gload_lds16(aga[j] + k0, alds[j]);
#pragma unroll
    for (int j = 0; j < 4; ++j) gload_lds16(bga[j] + k0, blds[j]);
    __syncthreads();

#pragma unroll
    for (int s = 0; s < 2; ++s) {
      int coff = ((s * 4 + quad) * 8) ^ swz8;
      v8s a[4], b[4];
#pragma unroll
      for (int mt = 0; mt < 4; ++mt)
        a[mt] = *reinterpret_cast<const v8s*>(&As[rowAoff[mt] + coff]);
#pragma unroll
      for (int nt = 0; nt < 4; ++nt)
        b[nt] = *reinterpret_cast<const v8s*>(&Bs[rowBoff[nt] + coff]);
#pragma unroll
      for (int mt = 0; mt < 4; ++mt)
#pragma unroll
        for (int nt = 0; nt < 4; ++nt)
          acc[mt][nt] = __builtin_amdgcn_mfma_f32_16x16x32_bf16(a[mt], b[nt], acc[mt][nt], 0, 0, 0);
    }
  }

  float b2v[4];
  int ng[4];
#pragma unroll
  for (int nt = 0; nt < 4; ++nt) {
    ng[nt] = n0 + wn + nt * 16 + l16;
    b2v[nt] = b2[(size_t)e * Dd + ng[nt]];
  }
#pragma unroll
  for (int mt = 0; mt < 4; ++mt) {
#pragma unroll
    for (int i = 0; i < 4; ++i) {
      int m = wm + mt * 16 + quad * 4 + i;
      if (sbase + m < lim) {
        size_t rowbase = (size_t)(sbase + m) * Dd;
#pragma unroll
        for (int nt = 0; nt < 4; ++nt)
          ybuf[rowbase + ng[nt]] = f2bf(acc[mt][nt][i] + b2v[nt]);
      }
    }
  }
}

// out[t] = w0 * y[slot0] + w1 * y[slot1]
__global__ __launch_bounds__(256) void combine_kernel(
    const u16* __restrict__ ybuf, const int* __restrict__ slotmap,
    const float* __restrict__ topkw, float* __restrict__ out) {
  int idx = blockIdx.x * 256 + threadIdx.x;
  int t = idx >> 7;
  int d0 = (idx & 127) * 8;
  int s0 = slotmap[2 * t], s1 = slotmap[2 * t + 1];
  float w0 = topkw[2 * t], w1 = topkw[2 * t + 1];
  uint4 ya = *reinterpret_cast<const uint4*>(ybuf + (size_t)s0 * Dd + d0);
  uint4 yb = *reinterpret_cast<const uint4*>(ybuf + (size_t)s1 * Dd + d0);
  float r[8];
  const unsigned* pa = &ya.x;
  const unsigned* pb = &yb.x;
#pragma unroll
  for (int j = 0; j < 4; ++j) {
    unsigned a = pa[j], b = pb[j];
    r[2 * j]     = w0 * bf2f((u16)(a & 0xffff)) + w1 * bf2f((u16)(b & 0xffff));
    r[2 * j + 1] = w0 * bf2f((u16)(a >> 16))    + w1 * bf2f((u16)(b >> 16));
  }
  float4* op = reinterpret_cast<float4*>(out + (size_t)t * Dd + d0);
  op[0] = make_float4(r[0], r[1], r[2], r[3]);
  op[1] = make_float4(r[4], r[5], r[6], r[7]);
}

extern "C" void kernel_launch(void* const* d_in, const int* in_sizes, int n_in,
                              void* d_out, int out_size, void* d_ws, size_t ws_size,
                              hipStream_t stream) {
  const float* x  = (const float*)d_in[0];
  const float* Wg = (const float*)d_in[2];
  const float* bg = (const float*)d_in[3];
  const float* W1 = (const float*)d_in[4];
  const float* b1 = (const float*)d_in[5];
  const float* W2 = (const float*)d_in[6];
  const float* b2 = (const float*)d_in[7];
  float* out = (float*)d_out;

  char* p = (char*)d_ws;
  auto take = [&](size_t bytes) {
    char* q = p;
    p += (bytes + 255) & ~(size_t)255;
    return q;
  };
  int*   offs       = (int*)take(64);
  int*   blockcnt   = (int*)take((size_t)NB * 8 * sizeof(int));
  int*   blockstart = (int*)take((size_t)NB * 8 * sizeof(int));
  int*   panelE     = (int*)take(1024);
  int*   panelB     = (int*)take(1024);
  int*   nPanels    = (int*)take(256);
  int*   topki      = (int*)take((size_t)Tn * 2 * sizeof(int));
  float* topkw      = (float*)take((size_t)Tn * 2 * sizeof(float));
  int*   rows       = (int*)take((size_t)Tn * 2 * sizeof(int));
  int*   slotmap    = (int*)take((size_t)Tn * 2 * sizeof(int));
  u16*   xb         = (u16*)take((size_t)Tn * Dd * 2);
  u16*   w1t        = (u16*)take((size_t)Ee * Dd * Hh * 2);
  u16*   w2t        = (u16*)take((size_t)Ee * Dd * Hh * 2);
  u16*   hbuf       = (u16*)take((size_t)Tn * 2 * Hh * 2);
  u16*   ybuf       = (u16*)take((size_t)Tn * 2 * Dd * 2);

  transpose_cvt_kernel<<<dim3(Hh / 64, Dd / 64, Ee), dim3(64, 8), 0, stream>>>(W1, w1t, Dd, Hh);
  transpose_cvt_kernel<<<dim3(Dd / 64, Hh / 64, Ee), dim3(64, 8), 0, stream>>>(W2, w2t, Hh, Dd);
  gating_kernel<<<Tn / 4, 256, 0, stream>>>(x, Wg, bg, topki, topkw, xb);
  hist_kernel<<<NB, 256, 0, stream>>>(topki, blockcnt);
  prefix_kernel<<<1, 64, 0, stream>>>(blockcnt, offs, blockstart, panelE, panelB, nPanels);
  scatter_kernel<<<NB, 256, 0, stream>>>(topki, blockstart, rows, slotmap);
  gemm1_kernel<<<8 * 16 * MAXP, 256, 0, stream>>>(xb, w1t, b1, offs, rows,
                                                  panelE, panelB, nPanels, hbuf);
  gemm2_kernel<<<8 * 8 * MAXP, 256, 0, stream>>>(hbuf, w2t, b2, offs,
                                                 panelE, panelB, nPanels, ybuf);
  combine_kernel<<<(Tn * Dd / 8) / 256, 256, 0, stream>>>(ybuf, slotmap, topkw, out);
}

// Round 8
// 439.693 us; speedup vs baseline: 1.3018x; 1.3018x over previous
//
#include <hip/hip_runtime.h>

typedef unsigned short u16;
typedef short v8s __attribute__((ext_vector_type(8)));
typedef float v4f __attribute__((ext_vector_type(4)));

constexpr int Tn = 8192;   // tokens = B*S
constexpr int Dd = 1024;   // model dim
constexpr int Hh = 2048;   // hidden dim
constexpr int Ee = 8;      // experts
constexpr int NB = 32;     // histogram/scatter blocks
constexpr int MAXP = 17;   // ceil(max 128-row panels / 8); panels <= 128+8=136

// round-to-nearest-even f32 -> bf16 (inputs finite)
static __device__ __forceinline__ u16 f2bf(float v) {
  unsigned u = __float_as_uint(v);
  unsigned r = (u + 0x7fffu + ((u >> 16) & 1u)) >> 16;
  return (u16)r;
}

static __device__ __forceinline__ float bf2f(u16 v) {
  return __uint_as_float(((unsigned)v) << 16);
}

// async global -> LDS, 16B per lane; LDS dest = wave-uniform base + lane*16
static __device__ __forceinline__ void gload_lds16(const u16* g, u16* l) {
  __builtin_amdgcn_global_load_lds(
      (const __attribute__((address_space(1))) unsigned int*)g,
      (__attribute__((address_space(3))) unsigned int*)l, 16, 0, 0);
}

// Fused: W1 [E][Dd][Hh] -> w1t [E][Hh][Dd] bf16 AND W2 [E][Hh][Dd] -> w2t [E][Dd][Hh] bf16.
// 64x64 tiles, block (64,8). Blocks [0,4096) = W1, [4096,8192) = W2.
__global__ __launch_bounds__(512) void transpose_cvt_kernel(
    const float* __restrict__ W1, u16* __restrict__ w1t,
    const float* __restrict__ W2, u16* __restrict__ w2t) {
  __shared__ float tile[64][65];
  int b = blockIdx.x;
  const float* in;
  u16* out;
  int R, C, cx, cy, e;
  if (b < 4096) {
    e = b >> 9;
    int t = b & 511;
    R = Dd; C = Hh; cx = t & 31; cy = t >> 5;       // 32 x 16 tiles
    in = W1; out = w1t;
  } else {
    int bb = b - 4096;
    e = bb >> 9;
    int t = bb & 511;
    R = Hh; C = Dd; cx = t & 15; cy = t >> 4;       // 16 x 32 tiles
    in = W2; out = w2t;
  }
  const float* ip = in + (size_t)e * Dd * Hh;
  u16* op = out + (size_t)e * Dd * Hh;
  int c0 = cx * 64, r0 = cy * 64;
  int tx = threadIdx.x, ty = threadIdx.y;
  for (int i = ty; i < 64; i += 8)
    tile[i][tx] = ip[(size_t)(r0 + i) * C + c0 + tx];
  __syncthreads();
  for (int i = ty; i < 64; i += 8)
    op[(size_t)(c0 + i) * R + r0 + tx] = f2bf(tile[tx][i]);
}

// one wave per token; fused x->bf16 conversion; no global atomics
__global__ __launch_bounds__(256) void gating_kernel(
    const float* __restrict__ x, const float* __restrict__ Wg, const float* __restrict__ bg,
    int* __restrict__ topki, float* __restrict__ topkw, u16* __restrict__ xb) {
  int lane = threadIdx.x & 63;
  int t = blockIdx.x * 4 + (threadIdx.x >> 6);
  const float4* xr = reinterpret_cast<const float4*>(x + (size_t)t * Dd);
  float acc[8] = {0.f, 0.f, 0.f, 0.f, 0.f, 0.f, 0.f, 0.f};
#pragma unroll
  for (int it = 0; it < 4; ++it) {
    float4 xv = xr[it * 64 + lane];
    int r = it * 256 + lane * 4;
    ushort4 o;
    o.x = f2bf(xv.x); o.y = f2bf(xv.y); o.z = f2bf(xv.z); o.w = f2bf(xv.w);
    *reinterpret_cast<ushort4*>(xb + (size_t)t * Dd + r) = o;
    const float4* wr = reinterpret_cast<const float4*>(Wg + (size_t)r * 8);
    float xs[4] = {xv.x, xv.y, xv.z, xv.w};
#pragma unroll
    for (int q = 0; q < 4; ++q) {
      float4 a = wr[q * 2], b = wr[q * 2 + 1];
      acc[0] += xs[q] * a.x; acc[1] += xs[q] * a.y; acc[2] += xs[q] * a.z; acc[3] += xs[q] * a.w;
      acc[4] += xs[q] * b.x; acc[5] += xs[q] * b.y; acc[6] += xs[q] * b.z; acc[7] += xs[q] * b.w;
    }
  }
#pragma unroll
  for (int e = 0; e < 8; ++e) {
#pragma unroll
    for (int off = 32; off > 0; off >>= 1) acc[e] += __shfl_xor(acc[e], off, 64);
  }
  if (lane == 0) {
    float l[8];
    float mx = -1e30f;
#pragma unroll
    for (int e = 0; e < 8; ++e) { l[e] = acc[e] + bg[e]; mx = fmaxf(mx, l[e]); }
    int i0 = 0;
#pragma unroll
    for (int e = 1; e < 8; ++e) if (l[e] > l[i0]) i0 = e;
    int i1 = (i0 == 0) ? 1 : 0;
#pragma unroll
    for (int e = 0; e < 8; ++e) if (e != i0 && l[e] > l[i1]) i1 = e;
    float e0 = __expf(l[i0] - mx), e1 = __expf(l[i1] - mx);
    float inv = 1.0f / (e0 + e1);
    topki[2 * t] = i0; topki[2 * t + 1] = i1;
    topkw[2 * t] = e0 * inv; topkw[2 * t + 1] = e1 * inv;
  }
}

// per-block expert histogram via LDS atomics; 8 global stores per block
__global__ __launch_bounds__(256) void hist_kernel(const int* __restrict__ topki,
                                                   int* __restrict__ blockcnt) {
  __shared__ int bins[8];
  int tid = threadIdx.x, b = blockIdx.x;
  if (tid < 8) bins[tid] = 0;
  __syncthreads();
  atomicAdd(&bins[topki[b * 512 + tid]], 1);
  atomicAdd(&bins[topki[b * 512 + 256 + tid]], 1);
  __syncthreads();
  if (tid < 8) blockcnt[b * 8 + tid] = bins[tid];
}

// prefix sums + XCD-pinned 128-row panel work-list
__global__ void prefix_kernel(const int* __restrict__ blockcnt, int* __restrict__ offs,
                              int* __restrict__ blockstart,
                              int* __restrict__ panelE, int* __restrict__ panelB,
                              int* __restrict__ nPanels) {
  __shared__ int tmp[8][NB];
  __shared__ int tot[8];
  int tid = threadIdx.x;
  if (tid < 8) {
    int s = 0;
    for (int b = 0; b < NB; ++b) { tmp[tid][b] = s; s += blockcnt[b * 8 + tid]; }
    tot[tid] = s;
  }
  __syncthreads();
  if (tid == 0) {
    int o = 0;
    for (int e = 0; e < 8; ++e) { offs[e] = o; o += tot[e]; }
    offs[8] = o;
    int np = 0;
    for (int e = 0; e < 8; ++e) {
      for (int m0 = 0; m0 < tot[e]; m0 += 128) {
        panelE[np] = e;
        panelB[np] = offs[e] + m0;
        ++np;
      }
    }
    *nPanels = np;
  }
  __syncthreads();
  if (tid < 8)
    for (int b = 0; b < NB; ++b) blockstart[b * 8 + tid] = offs[tid] + tmp[tid][b];
}

// slot assignment with LDS-local ranks; zero global atomics
__global__ __launch_bounds__(256) void scatter_kernel(
    const int* __restrict__ topki, const int* __restrict__ blockstart,
    int* __restrict__ rows, int* __restrict__ slotmap) {
  __shared__ int lbins[8];
  int tid = threadIdx.x, b = blockIdx.x;
  if (tid < 8) lbins[tid] = blockstart[b * 8 + tid];
  __syncthreads();
#pragma unroll
  for (int j = 0; j < 2; ++j) {
    int idx = b * 512 + j * 256 + tid;
    int e = topki[idx];
    int slot = atomicAdd(&lbins[e], 1);
    rows[slot] = idx >> 1;
    slotmap[idx] = slot;
  }
}

// ---- GEMM cores: 128x128 tile, BK=64, XOR-swizzled LDS (R5 config: best known) ----
// NOTE: (256,2) only — (256,4) caps unified VGPR+AGPR at 128 < ~136 needed -> scratch
// spill -> 240 MB of extra HBM traffic (measured R7). Residency is ~3 blocks/CU.

// GEMM1: h[slot][n] = gelu( x[rows[slot]] @ W1[e] + b1[e] )
__global__ __launch_bounds__(256, 2) void gemm1_kernel(
    const u16* __restrict__ xb, const u16* __restrict__ w1t, const float* __restrict__ b1,
    const int* __restrict__ offs, const int* __restrict__ rows,
    const int* __restrict__ panelE, const int* __restrict__ panelB,
    const int* __restrict__ nPanels, u16* __restrict__ hbuf) {
  const int bid = blockIdx.x;
  const int xcd = bid & 7;
  const int q = bid >> 3;
  const int n = q & 15;               // Hh/128 = 16 n-blocks
  const int pi = (q >> 4) * 8 + xcd;
  if (pi >= *nPanels) return;
  const int e = panelE[pi];
  const int sbase = panelB[pi];
  const int lim = offs[e + 1];
  const int n0 = n * 128;

  __shared__ u16 As[128 * 64];        // 16 KB
  __shared__ u16 Bs[128 * 64];        // 16 KB

  const int tid = threadIdx.x;
  const int lane = tid & 63;
  const int wid = tid >> 6;
  const int wm = (wid >> 1) * 64;
  const int wn = (wid & 1) * 64;
  const int l16 = lane & 15;
  const int quad = lane >> 4;
  const int swz8 = (l16 & 7) * 8;     // read-side XOR mask (elems)

  const u16* aga[4];
  const u16* bga[4];
  u16* alds[4];
  u16* blds[4];
  const int lr = lane >> 3;                 // row within 8-row chunk
  const int g = (lane & 7) ^ (lr & 7);      // staged global k-chunk (XOR swizzle)
  const int kcol = g * 8;
#pragma unroll
  for (int j = 0; j < 4; ++j) {
    int chunk = wid * 4 + j;                // 0..15 covers rows [chunk*8, chunk*8+8)
    int rowl = chunk * 8 + lr;
    int slot = sbase + rowl;
    if (slot >= lim) slot = sbase;
    aga[j] = xb + (size_t)rows[slot] * Dd + kcol;
    bga[j] = w1t + ((size_t)e * Hh + n0 + rowl) * Dd + kcol;
    alds[j] = As + chunk * 512;             // 1 KB per wave-instruction
    blds[j] = Bs + chunk * 512;
  }

  v4f acc[4][4];
#pragma unroll
  for (int i = 0; i < 4; ++i)
#pragma unroll
    for (int j = 0; j < 4; ++j) acc[i][j] = {0.f, 0.f, 0.f, 0.f};

  int rowAoff[4], rowBoff[4];
#pragma unroll
  for (int t_ = 0; t_ < 4; ++t_) {
    rowAoff[t_] = (wm + t_ * 16 + l16) * 64;
    rowBoff[t_] = (wn + t_ * 16 + l16) * 64;
  }

  for (int k0 = 0; k0 < Dd; k0 += 64) {
    __syncthreads();
#pragma unroll
    for (int j = 0; j < 4; ++j) gload_lds16(aga[j] + k0, alds[j]);
#pragma unroll
    for (int j = 0; j < 4; ++j) gload_lds16(bga[j] + k0, blds[j]);
    __syncthreads();

#pragma unroll
    for (int s = 0; s < 2; ++s) {
      int coff = ((s * 4 + quad) * 8) ^ swz8;
      v8s a[4], b[4];
#pragma unroll
      for (int mt = 0; mt < 4; ++mt)
        a[mt] = *reinterpret_cast<const v8s*>(&As[rowAoff[mt] + coff]);
#pragma unroll
      for (int nt = 0; nt < 4; ++nt)
        b[nt] = *reinterpret_cast<const v8s*>(&Bs[rowBoff[nt] + coff]);
#pragma unroll
      for (int mt = 0; mt < 4; ++mt)
#pragma unroll
        for (int nt = 0; nt < 4; ++nt)
          acc[mt][nt] = __builtin_amdgcn_mfma_f32_16x16x32_bf16(a[mt], b[nt], acc[mt][nt], 0, 0, 0);
    }
  }

  float b1v[4];
  int ng[4];
#pragma unroll
  for (int nt = 0; nt < 4; ++nt) {
    ng[nt] = n0 + wn + nt * 16 + l16;
    b1v[nt] = b1[(size_t)e * Hh + ng[nt]];
  }
#pragma unroll
  for (int mt = 0; mt < 4; ++mt) {
#pragma unroll
    for (int i = 0; i < 4; ++i) {
      int m = wm + mt * 16 + quad * 4 + i;
      if (sbase + m < lim) {
        size_t rowbase = (size_t)(sbase + m) * Hh;
#pragma unroll
        for (int nt = 0; nt < 4; ++nt) {
          float v = acc[mt][nt][i] + b1v[nt];
          float s = 1.0f / (1.0f + __expf(-1.5957691216057308f * (v + 0.044715f * v * v * v)));
          hbuf[rowbase + ng[nt]] = f2bf(v * s);
        }
      }
    }
  }
}

// GEMM2: ybuf[slot][n] = h[slot] @ W2[e] + b2[e]
__global__ __launch_bounds__(256, 2) void gemm2_kernel(
    const u16* __restrict__ hbuf, const u16* __restrict__ w2t, const float* __restrict__ b2,
    const int* __restrict__ offs,
    const int* __restrict__ panelE, const int* __restrict__ panelB,
    const int* __restrict__ nPanels, u16* __restrict__ ybuf) {
  const int bid = blockIdx.x;
  const int xcd = bid & 7;
  const int q = bid >> 3;
  const int n = q & 7;                // Dd/128 = 8 n-blocks
  const int pi = (q >> 3) * 8 + xcd;
  if (pi >= *nPanels) return;
  const int e = panelE[pi];
  const int sbase = panelB[pi];
  const int lim = offs[e + 1];
  const int n0 = n * 128;

  __shared__ u16 As[128 * 64];
  __shared__ u16 Bs[128 * 64];

  const int tid = threadIdx.x;
  const int lane = tid & 63;
  const int wid = tid >> 6;
  const int wm = (wid >> 1) * 64;
  const int wn = (wid & 1) * 64;
  const int l16 = lane & 15;
  const int quad = lane >> 4;
  const int swz8 = (l16 & 7) * 8;

  const u16* aga[4];
  const u16* bga[4];
  u16* alds[4];
  u16* blds[4];
  const int lr = lane >> 3;
  const int g = (lane & 7) ^ (lr & 7);
  const int kcol = g * 8;
#pragma unroll
  for (int j = 0; j < 4; ++j) {
    int chunk = wid * 4 + j;
    int rowl = chunk * 8 + lr;
    int slot = sbase + rowl;
    if (slot >= lim) slot = sbase;
    aga[j] = hbuf + (size_t)slot * Hh + kcol;
    bga[j] = w2t + ((size_t)e * Dd + n0 + rowl) * Hh + kcol;
    alds[j] = As + chunk * 512;
    blds[j] = Bs + chunk * 512;
  }

  v4f acc[4][4];
#pragma unroll
  for (int i = 0; i < 4; ++i)
#pragma unroll
    for (int j = 0; j < 4; ++j) acc[i][j] = {0.f, 0.f, 0.f, 0.f};

  int rowAoff[4], rowBoff[4];
#pragma unroll
  for (int t_ = 0; t_ < 4; ++t_) {
    rowAoff[t_] = (wm + t_ * 16 + l16) * 64;
    rowBoff[t_] = (wn + t_ * 16 + l16) * 64;
  }

  for (int k0 = 0; k0 < Hh; k0 += 64) {
    __syncthreads();
#pragma unroll
    for (int j = 0; j < 4; ++j) gload_lds16(aga[j] + k0, alds[j]);
#pragma unroll
    for (int j = 0; j < 4; ++j) gload_lds16(bga[j] + k0, blds[j]);
    __syncthreads();

#pragma unroll
    for (int s = 0; s < 2; ++s) {
      int coff = ((s * 4 + quad) * 8) ^ swz8;
      v8s a[4], b[4];
#pragma unroll
      for (int mt = 0; mt < 4; ++mt)
        a[mt] = *reinterpret_cast<const v8s*>(&As[rowAoff[mt] + coff]);
#pragma unroll
      for (int nt = 0; nt < 4; ++nt)
        b[nt] = *reinterpret_cast<const v8s*>(&Bs[rowBoff[nt] + coff]);
#pragma unroll
      for (int mt = 0; mt < 4; ++mt)
#pragma unroll
        for (int nt = 0; nt < 4; ++nt)
          acc[mt][nt] = __builtin_amdgcn_mfma_f32_16x16x32_bf16(a[mt], b[nt], acc[mt][nt], 0, 0, 0);
    }
  }

  float b2v[4];
  int ng[4];
#pragma unroll
  for (int nt = 0; nt < 4; ++nt) {
    ng[nt] = n0 + wn + nt * 16 + l16;
    b2v[nt] = b2[(size_t)e * Dd + ng[nt]];
  }
#pragma unroll
  for (int mt = 0; mt < 4; ++mt) {
#pragma unroll
    for (int i = 0; i < 4; ++i) {
      int m = wm + mt * 16 + quad * 4 + i;
      if (sbase + m < lim) {
        size_t rowbase = (size_t)(sbase + m) * Dd;
#pragma unroll
        for (int nt = 0; nt < 4; ++nt)
          ybuf[rowbase + ng[nt]] = f2bf(acc[mt][nt][i] + b2v[nt]);
      }
    }
  }
}

// out[t] = w0 * y[slot0] + w1 * y[slot1]
__global__ __launch_bounds__(256) void combine_kernel(
    const u16* __restrict__ ybuf, const int* __restrict__ slotmap,
    const float* __restrict__ topkw, float* __restrict__ out) {
  int idx = blockIdx.x * 256 + threadIdx.x;
  int t = idx >> 7;
  int d0 = (idx & 127) * 8;
  int s0 = slotmap[2 * t], s1 = slotmap[2 * t + 1];
  float w0 = topkw[2 * t], w1 = topkw[2 * t + 1];
  uint4 ya = *reinterpret_cast<const uint4*>(ybuf + (size_t)s0 * Dd + d0);
  uint4 yb = *reinterpret_cast<const uint4*>(ybuf + (size_t)s1 * Dd + d0);
  float r[8];
  const unsigned* pa = &ya.x;
  const unsigned* pb = &yb.x;
#pragma unroll
  for (int j = 0; j < 4; ++j) {
    unsigned a = pa[j], b = pb[j];
    r[2 * j]     = w0 * bf2f((u16)(a & 0xffff)) + w1 * bf2f((u16)(b & 0xffff));
    r[2 * j + 1] = w0 * bf2f((u16)(a >> 16))    + w1 * bf2f((u16)(b >> 16));
  }
  float4* op = reinterpret_cast<float4*>(out + (size_t)t * Dd + d0);
  op[0] = make_float4(r[0], r[1], r[2], r[3]);
  op[1] = make_float4(r[4], r[5], r[6], r[7]);
}

extern "C" void kernel_launch(void* const* d_in, const int* in_sizes, int n_in,
                              void* d_out, int out_size, void* d_ws, size_t ws_size,
                              hipStream_t stream) {
  const float* x  = (const float*)d_in[0];
  const float* Wg = (const float*)d_in[2];
  const float* bg = (const float*)d_in[3];
  const float* W1 = (const float*)d_in[4];
  const float* b1 = (const float*)d_in[5];
  const float* W2 = (const float*)d_in[6];
  const float* b2 = (const float*)d_in[7];
  float* out = (float*)d_out;

  char* p = (char*)d_ws;
  auto take = [&](size_t bytes) {
    char* q = p;
    p += (bytes + 255) & ~(size_t)255;
    return q;
  };
  int*   offs       = (int*)take(64);
  int*   blockcnt   = (int*)take((size_t)NB * 8 * sizeof(int));
  int*   blockstart = (int*)take((size_t)NB * 8 * sizeof(int));
  int*   panelE     = (int*)take(1024);
  int*   panelB     = (int*)take(1024);
  int*   nPanels    = (int*)take(256);
  int*   topki      = (int*)take((size_t)Tn * 2 * sizeof(int));
  float* topkw      = (float*)take((size_t)Tn * 2 * sizeof(float));
  int*   rows       = (int*)take((size_t)Tn * 2 * sizeof(int));
  int*   slotmap    = (int*)take((size_t)Tn * 2 * sizeof(int));
  u16*   xb         = (u16*)take((size_t)Tn * Dd * 2);
  u16*   w1t        = (u16*)take((size_t)Ee * Dd * Hh * 2);
  u16*   w2t        = (u16*)take((size_t)Ee * Dd * Hh * 2);
  u16*   hbuf       = (u16*)take((size_t)Tn * 2 * Hh * 2);
  u16*   ybuf       = (u16*)take((size_t)Tn * 2 * Dd * 2);

  transpose_cvt_kernel<<<8192, dim3(64, 8), 0, stream>>>(W1, w1t, W2, w2t);
  gating_kernel<<<Tn / 4, 256, 0, stream>>>(x, Wg, bg, topki, topkw, xb);
  hist_kernel<<<NB, 256, 0, stream>>>(topki, blockcnt);
  prefix_kernel<<<1, 64, 0, stream>>>(blockcnt, offs, blockstart, panelE, panelB, nPanels);
  scatter_kernel<<<NB, 256, 0, stream>>>(topki, blockstart, rows, slotmap);
  gemm1_kernel<<<8 * 16 * MAXP, 256, 0, stream>>>(xb, w1t, b1, offs, rows,
                                                  panelE, panelB, nPanels, hbuf);
  gemm2_kernel<<<8 * 8 * MAXP, 256, 0, stream>>>(hbuf, w2t, b2, offs,
                                                 panelE, panelB, nPanels, ybuf);
  combine_kernel<<<(Tn * Dd / 8) / 256, 256, 0, stream>>>(ybuf, slotmap, topkw, out);
}